// Round 5
// baseline (164.121 us; speedup 1.0000x reference)
//
#include <hip/hip_runtime.h>
#include <hip/hip_fp16.h>

#define DIM 128
#define KK 3
#define RPB 16       // rows per fused block (one MFMA M-tile)
#define ZPAD 392     // zs row stride in shorts
#define EBLK 4096    // edges per pass-A block
#define NBKT 256     // coarse bucket space (row>>8); 196 used at n=50000
#define CAPB 5120    // records per bucket region (mean 4082, +16 sigma)
#define QF   512     // K2 LDS stream chunk (records); tile mean 256, sigma 16
#define OVF_CAP 65536

typedef __attribute__((ext_vector_type(4))) float f32x4;
typedef __attribute__((ext_vector_type(8))) short bf16x8;

__device__ __forceinline__ unsigned pkbf(float lo, float hi) {
    unsigned a = __float_as_uint(lo), b = __float_as_uint(hi);
    a = (a + 0x7fffu + ((a >> 16) & 1u)) >> 16;
    b = (b + 0x7fffu + ((b >> 16) & 1u)) & 0xffff0000u;
    return (a & 0xffffu) | b;
}

// ---------- K1a: xcast + W B-fragments (streaming, no scatter) ----------
__global__ __launch_bounds__(256) void k1a_kernel(
        const float* __restrict__ x, const float* __restrict__ w,
        uint2* __restrict__ xb2q, bf16x8* __restrict__ wbf,
        int xq_total, int xblk) {
    int b = blockIdx.x;
    if (b < xblk) {
        int i = b * 256 + threadIdx.x;
        if (i < xq_total) {
            float4 v = ((const float4*)x)[i];
            xb2q[i] = make_uint2(pkbf(v.x, v.y), pkbf(v.z, v.w));
        }
    } else {
        int t = (b - xblk) * 256 + threadIdx.x;
        if (t < 12 * 8 * 64) {
            int lane = t & 63;
            int quad = lane >> 4;
            int nn = ((t >> 6) & 7) * 16 + (lane & 15);
            int kbase = (t >> 9) * 32 + quad * 8;
            short vals[8];
#pragma unroll
            for (int j = 0; j < 8; ++j) {
                int k = kbase + j;
                int k3 = k >> 7, i2 = k & (DIM - 1);
                unsigned bv = __float_as_uint(w[((size_t)i2 * DIM + nn) * KK + k3]);
                vals[j] = (short)((bv + 0x7fffu + ((bv >> 16) & 1u)) >> 16);
            }
            wbf[t] = *(const bf16x8*)vals;
        }
    }
}

// ---------- Pass A: LDS multisplit by coarse bucket (row>>8) ----------
// Records are {col|row<<16, t0_f32, t1_f32, t2_f32}: no f16 packing, so the
// hot fused loop later needs zero conversion instructions per edge.
__global__ __launch_bounds__(1024) void binA_kernel(
        const float* __restrict__ TT, const int* __restrict__ eidx,
        int* __restrict__ bucketCnt, uint4* __restrict__ rec16,
        int* __restrict__ ovf_cnt, uint4* __restrict__ ovf, int E) {
    __shared__ unsigned sw0[EBLK], sw1[EBLK], sw2[EBLK], sw3[EBLK]; // 64KB
    __shared__ int hist[NBKT], scn[NBKT], cursor[NBKT], gbase[NBKT];
    int tid = threadIdx.x, blk = blockIdx.x;
    int e0 = blk * EBLK;
    int nval = min(EBLK, E - e0);

    if (tid < NBKT) hist[tid] = 0;
    __syncthreads();

    // phase 1: load 4 edges/thread, histogram coarse bucket
    unsigned w0v[4], w1v[4], w2v[4], w3v[4];
    int bv[4];
#pragma unroll
    for (int i = 0; i < 4; ++i) {
        int li = tid + i * 1024;
        bv[i] = -1;
        if (li < nval) {
            int e = e0 + li;
            int row = eidx[e];
            int col = eidx[(size_t)E + e];
            w0v[i] = (unsigned)col | ((unsigned)row << 16);
            w1v[i] = __float_as_uint(TT[(size_t)e * 3 + 0]);
            w2v[i] = __float_as_uint(TT[(size_t)e * 3 + 1]);
            w3v[i] = __float_as_uint(TT[(size_t)e * 3 + 2]);
            bv[i] = row >> 8;
            atomicAdd(&hist[bv[i]], 1);
        }
    }
    __syncthreads();

    // phase 2: exclusive scan over 256 bucket counts (Hillis-Steele)
    if (tid < NBKT) scn[tid] = hist[tid];
    __syncthreads();
    for (int d = 1; d < NBKT; d <<= 1) {
        int v = 0;
        if (tid < NBKT && tid >= d) v = scn[tid - d];
        __syncthreads();
        if (tid < NBKT && tid >= d) scn[tid] += v;
        __syncthreads();
    }
    if (tid < NBKT) {
        int ex = scn[tid] - hist[tid];
        scn[tid] = ex;
        cursor[tid] = ex;
        gbase[tid] = atomicAdd(&bucketCnt[tid], hist[tid]);  // 1 atomic/bucket
    }
    __syncthreads();

    // phase 3: scatter records into LDS, bucket-sorted
#pragma unroll
    for (int i = 0; i < 4; ++i) {
        if (bv[i] >= 0) {
            int lpos = atomicAdd(&cursor[bv[i]], 1);
            sw0[lpos] = w0v[i]; sw1[lpos] = w1v[i];
            sw2[lpos] = w2v[i]; sw3[lpos] = w3v[i];
        }
    }
    __syncthreads();

    // phase 4: flush bucket runs to fixed-stride global regions (semi-coalesced)
    for (int s = tid; s < nval; s += 1024) {
        unsigned u0 = sw0[s];
        int bb = (int)(u0 >> 24);                // row>>8 (row = u0>>16)
        int gpos = gbase[bb] + (s - scn[bb]);
        if (gpos < CAPB) {
            rec16[(size_t)bb * CAPB + gpos] = make_uint4(u0, sw1[s], sw2[s], sw3[s]);
        } else {
            int op = atomicAdd(ovf_cnt, 1);
            if (op < OVF_CAP)
                ovf[op] = make_uint4(u0, sw1[s], sw2[s], sw3[s]);
        }
    }
}

// ---------- Pass B: per-bucket fine sort (row&255) -> CSR + compact ----------
// Zero global atomics; all global writes coalesced.
__global__ __launch_bounds__(1024) void binB_kernel(
        const uint4* __restrict__ rec16, const int* __restrict__ bucketCnt,
        uint4* __restrict__ out16, int* __restrict__ rowStart,
        int* __restrict__ rowCnt) {
    __shared__ uint4 ostage[CAPB];                          // 80KB
    __shared__ int hist[256], scn[256], cursor[256];
    int b = blockIdx.x, tid = threadIdx.x;
    int cntb = min(bucketCnt[b], CAPB);

    if (tid < 256) hist[tid] = 0;
    __syncthreads();
    for (int i = tid; i < cntb; i += 1024) {
        unsigned u0 = rec16[(size_t)b * CAPB + i].x;
        atomicAdd(&hist[(u0 >> 16) & 255u], 1);
    }
    __syncthreads();
    if (tid < 256) scn[tid] = hist[tid];
    __syncthreads();
    for (int d = 1; d < 256; d <<= 1) {
        int v = 0;
        if (tid < 256 && tid >= d) v = scn[tid - d];
        __syncthreads();
        if (tid < 256 && tid >= d) scn[tid] += v;
        __syncthreads();
    }
    if (tid < 256) {
        int ex = scn[tid] - hist[tid];
        scn[tid] = ex;
        cursor[tid] = ex;
        rowStart[b * 256 + tid] = b * CAPB + ex;            // CSR (fixed-stride)
        rowCnt[b * 256 + tid] = hist[tid];
    }
    __syncthreads();
    for (int i = tid; i < cntb; i += 1024) {
        uint4 r = rec16[(size_t)b * CAPB + i];              // L2-hot re-read
        int rl = (int)((r.x >> 16) & 255u);
        int pos = atomicAdd(&cursor[rl], 1);
        ostage[pos] = r;
    }
    __syncthreads();
    for (int i = tid; i < cntb; i += 1024)
        out16[(size_t)b * CAPB + i] = ostage[i];            // coalesced flush
}

// ---------- K2: fused CSR aggregate + MFMA gemm ----------
// record: {col|rl<<16, t0f, t1f, t2f} -> zero cvt per edge; ~12 inst/edge
__device__ __forceinline__ void edge_fma(uint4 rc, const unsigned* __restrict__ xb2, int lane,
        float& a0l, float& a0h, float& a1l, float& a1h, float& a2l, float& a2h) {
    int c = rc.x & 0xffffu;
    float t0 = __uint_as_float(rc.y);
    float t1 = __uint_as_float(rc.z);
    float t2 = __uint_as_float(rc.w);
    unsigned u = xb2[(size_t)c * 64 + lane];
    float xl = __uint_as_float(u << 16), xh = __uint_as_float(u & 0xffff0000u);
    a0l = fmaf(t0, xl, a0l); a0h = fmaf(t0, xh, a0h);
    a1l = fmaf(t1, xl, a1l); a1h = fmaf(t1, xh, a1h);
    a2l = fmaf(t2, xl, a2l); a2h = fmaf(t2, xh, a2h);
}

__global__ __launch_bounds__(256) void fused_kernel(const uint4* __restrict__ out16,
        const int* __restrict__ rowStart, const int* __restrict__ rowCnt,
        const unsigned* __restrict__ xb2, const bf16x8* __restrict__ wbf,
        const float* __restrict__ bias, float* __restrict__ out, int n) {
    __shared__ short zs16[RPB][ZPAD];
    __shared__ uint4 qflat[QF];
    __shared__ int rs[RPB], rc[RPB];
    int tid = threadIdx.x;
    int lane = tid & 63, wv = tid >> 6;
    int n0 = blockIdx.x * RPB;   // 16-row tile; 16 | 256 so one coarse bucket

    if (tid < RPB) {
        int r = n0 + tid;
        rs[tid] = (r < n) ? rowStart[r] : 0;
        rc[tid] = (r < n) ? rowCnt[r] : 0;
    }
    __syncthreads();
    int base = rs[0];
    int tot = rs[RPB - 1] + rc[RPB - 1] - base;   // contiguous CSR range

    float A[4][6];
#pragma unroll
    for (int ii = 0; ii < 4; ++ii)
#pragma unroll
        for (int j = 0; j < 6; ++j) A[ii][j] = 0.f;

    for (int c0 = 0; c0 < tot; c0 += QF) {
        int cl = min(QF, tot - c0);
        __syncthreads();
        for (int i = tid; i < cl; i += 256) qflat[i] = out16[(size_t)base + c0 + i];
        __syncthreads();
#pragma unroll
        for (int ii = 0; ii < 4; ++ii) {
            int rl = wv * 4 + ii;
            int s = rs[rl] - base, e = s + rc[rl];
            int lo = max(s, c0), hi = min(e, c0 + cl);
            int p = lo;
            // unroll 8: 8 gathers in flight per wave (MLP for latency hiding)
            for (; p + 8 <= hi; p += 8) {
#pragma unroll
                for (int u8 = 0; u8 < 8; ++u8)
                    edge_fma(qflat[p - c0 + u8], xb2, lane,
                             A[ii][0], A[ii][1], A[ii][2], A[ii][3], A[ii][4], A[ii][5]);
            }
            for (; p + 4 <= hi; p += 4) {
#pragma unroll
                for (int u4 = 0; u4 < 4; ++u4)
                    edge_fma(qflat[p - c0 + u4], xb2, lane,
                             A[ii][0], A[ii][1], A[ii][2], A[ii][3], A[ii][4], A[ii][5]);
            }
            for (; p < hi; ++p)
                edge_fma(qflat[p - c0], xb2, lane,
                         A[ii][0], A[ii][1], A[ii][2], A[ii][3], A[ii][4], A[ii][5]);
        }
    }

#pragma unroll
    for (int ii = 0; ii < 4; ++ii) {
        int rl = wv * 4 + ii;
        *(unsigned*)&zs16[rl][0 * DIM + 2 * lane] = pkbf(A[ii][0], A[ii][1]);
        *(unsigned*)&zs16[rl][1 * DIM + 2 * lane] = pkbf(A[ii][2], A[ii][3]);
        *(unsigned*)&zs16[rl][2 * DIM + 2 * lane] = pkbf(A[ii][4], A[ii][5]);
    }
    __syncthreads();

    // MFMA: M=16 rows, N=128 (2 x 16-tiles per wave), K=384 (12 steps)
    int quad = lane >> 4, m = lane & 15;
    int nt0 = wv * 2, nt1 = wv * 2 + 1;
    f32x4 acc0 = {0.f, 0.f, 0.f, 0.f}, acc1 = {0.f, 0.f, 0.f, 0.f};
#pragma unroll
    for (int kt = 0; kt < 12; ++kt) {
        bf16x8 a  = *(const bf16x8*)&zs16[m][kt * 32 + quad * 8];
        bf16x8 b0 = wbf[(kt * 8 + nt0) * 64 + lane];
        bf16x8 b1 = wbf[(kt * 8 + nt1) * 64 + lane];
        acc0 = __builtin_amdgcn_mfma_f32_16x16x32_bf16(a, b0, acc0, 0, 0, 0);
        acc1 = __builtin_amdgcn_mfma_f32_16x16x32_bf16(a, b1, acc1, 0, 0, 0);
    }
    // C/D layout: col(n)=lane&15, row(m)=quad*4+reg  [m89-verified]
    float bi0 = bias[nt0 * 16 + m], bi1 = bias[nt1 * 16 + m];
#pragma unroll
    for (int rr = 0; rr < 4; ++rr) {
        int node = n0 + quad * 4 + rr;
        if (node < n) {
            out[(size_t)node * DIM + nt0 * 16 + m] = acc0[rr] + bi0;
            out[(size_t)node * DIM + nt1 * 16 + m] = acc1[rr] + bi1;
        }
    }
}

// ---------- K3: exact replay of overflow edges (expected: none) ----------
__global__ __launch_bounds__(128) void ovf_kernel(const uint4* __restrict__ ovf,
        const int* __restrict__ ovf_cnt, const float* __restrict__ x,
        const float* __restrict__ w, float* __restrict__ out) {
    int total = min(*ovf_cnt, OVF_CAP);
    int d = threadIdx.x;
    for (int i = blockIdx.x; i < total; i += gridDim.x) {
        uint4 r = ovf[i];
        int col = (int)(r.x & 0xffffu), row = (int)(r.x >> 16);
        float t0 = __uint_as_float(r.y);
        float t1 = __uint_as_float(r.z);
        float t2 = __uint_as_float(r.w);
        float acc = 0.f;
        for (int ii = 0; ii < DIM; ++ii) {
            const float* wp = &w[((size_t)ii * DIM + d) * KK];
            acc = fmaf(x[(size_t)col * DIM + ii],
                       t0 * wp[0] + t1 * wp[1] + t2 * wp[2], acc);
        }
        atomicAdd(&out[(size_t)row * DIM + d], acc);
    }
}

extern "C" void kernel_launch(void* const* d_in, const int* in_sizes, int n_in,
                              void* d_out, int out_size, void* d_ws, size_t ws_size,
                              hipStream_t stream) {
    const float* x    = (const float*)d_in[0];
    const float* TT   = (const float*)d_in[1];
    const float* w    = (const float*)d_in[2];
    const float* bias = (const float*)d_in[3];
    const int*   eidx = (const int*)d_in[4];
    float* out = (float*)d_out;

    int n = in_sizes[0] / DIM;     // 50000 (< 65536: row/col pack in 16 bits)
    int E = in_sizes[1] / KK;      // 800000
    int nbkt = (n + 255) >> 8;     // 196 coarse buckets

    char* ws = (char*)d_ws;
    size_t o = 0;
    auto take = [&](size_t b) { void* p = ws + o; o += (b + 255) & ~(size_t)255; return p; };
    uint4*    rec16 = (uint4*)take((size_t)nbkt * CAPB * 16);   // 16.1 MB
    uint4*    out16 = (uint4*)take((size_t)nbkt * CAPB * 16);   // 16.1 MB
    int*      rowStart = (int*)take((size_t)nbkt * 256 * 4);    //  200 KB
    int*      rowCnt   = (int*)take((size_t)nbkt * 256 * 4);    //  200 KB
    int*      bcnt  = (int*)take((size_t)(NBKT + 64) * 4);      // bucketCnt+ovf_cnt
    uint4*    ovf   = (uint4*)take((size_t)OVF_CAP * 16);       //  1 MB
    bf16x8*   wbf   = (bf16x8*)take((size_t)12 * 8 * 64 * 16);  //  786 KB
    unsigned* xb2   = (unsigned*)take((size_t)n * DIM * 2);     // 12.8 MB
    (void)ws_size;
    int* ovf_cnt = bcnt + NBKT;

    hipMemsetAsync(bcnt, 0, (size_t)(NBKT + 64) * 4, stream);   // 1.3 KB only

    int xq = n * DIM / 4;
    int xblk = (xq + 255) / 256;          // 6250
    int ablk = (E + EBLK - 1) / EBLK;     // 196

    k1a_kernel<<<xblk + 24, 256, 0, stream>>>(x, w, (uint2*)xb2, wbf, xq, xblk);
    binA_kernel<<<ablk, 1024, 0, stream>>>(TT, eidx, bcnt, rec16, ovf_cnt, ovf, E);
    binB_kernel<<<nbkt, 1024, 0, stream>>>(rec16, bcnt, out16, rowStart, rowCnt);
    fused_kernel<<<(n + RPB - 1) / RPB, 256, 0, stream>>>(
        out16, rowStart, rowCnt, xb2, wbf, bias, out, n);
    ovf_kernel<<<64, 128, 0, stream>>>(ovf, ovf_cnt, x, w, out);
}